// Round 7
// baseline (227.666 us; speedup 1.0000x reference)
//
#include <hip/hip_runtime.h>

typedef float f4 __attribute__((ext_vector_type(4)));

static __device__ __forceinline__ f4 vexp2(f4 a) {
  f4 r;
  r.x = __builtin_amdgcn_exp2f(a.x);
  r.y = __builtin_amdgcn_exp2f(a.y);
  r.z = __builtin_amdgcn_exp2f(a.z);
  r.w = __builtin_amdgcn_exp2f(a.w);
  return r;
}
static __device__ __forceinline__ f4 fmax4(f4 a, f4 b) {
  f4 r;
  r.x = fmaxf(a.x, b.x); r.y = fmaxf(a.y, b.y);
  r.z = fmaxf(a.z, b.z); r.w = fmaxf(a.w, b.w);
  return r;
}

#define LOG2E 1.4426950408889634f
#define TILE 16
#define ROWS (TILE + 3)   // 19 staged padded rows per tile

// Grid: 8(b) x 8(h-tile) x 32(channel pair) = 2048 blocks, 256 threads.
// Thread = (w = t&127, cg = t>>7) owns ONE channel c = cp*2+cg and marches
// down TILE output rows. The 4x4 conv-tap window (kk/vv, f4 per column over
// row-slots) slides in registers: each step computes only the entering row
// (24 FMA + 12 conflict-free ds_read_b32) instead of all 16 taps.
// Row-slot index (phi+3)&3 is compile-time via the unrolled phi loop, so
// taps stay in registers (no dynamic vector indexing -> no scratch).
// Staging uses shift-only addressing (R6 lesson: div/mod staging replicated
// across blocks dominated VALU). Plain C++ vector math only (R5 lesson:
// inline-asm v_pk_* broke correctness). launch_bounds(256,4) proven safe;
// (256,8) caused a 32-VGPR scratch disaster (R3).
__global__ __launch_bounds__(256, 4) void stem_kernel(
    const float* __restrict__ x,    // [8,3,128,128]
    const float* __restrict__ qwp,  // [64,3]
    const float* __restrict__ kwp,  // [64,3]
    const float* __restrict__ vwp,  // [64,3]
    const float* __restrict__ ea,   // [64,128]  (c, w)
    const float* __restrict__ eb,   // [64,128]  (c, h)
    const float* __restrict__ em,   // [64,128,128] (c, h, w)
    float* __restrict__ out)        // [8,64,128,128]
{
  __shared__ float xs[3][ROWS][132];   // 30.1 KB

  const int blk = blockIdx.x;
  const int cp = blk & 31;           // channel pair index
  const int ht = (blk >> 5) & 7;     // h tile
  const int b  = blk >> 8;
  const int h0 = ht * TILE;
  const int t  = threadIdx.x;

  // ---- stage: interior cols via shift-only addressing, pads separately.
  {
    const float* xb = x + b * (3 * 128 * 128);
    for (int idx = t; idx < 3 * ROWS * 128; idx += 256) {
      int row = idx >> 7;                 // 0..56 = cin*ROWS + rr
      int wp2 = idx & 127;                // dest col wp2+2, source col wp2
      int cin = (row >= ROWS) + (row >= 2 * ROWS);
      int rr  = row - cin * ROWS;
      int g   = h0 - 2 + rr;              // source row (may be OOB -> 0)
      float v = 0.f;
      if ((unsigned)g < 128u) v = xb[(cin * 128 + g) * 128 + wp2];
      xs[cin][rr][wp2 + 2] = v;
    }
    if (t < 3 * ROWS * 4) {               // pad cols {0,1,130,131} = 0
      int row = t >> 2;
      int col = t & 3;
      int wp  = (col & 1) + ((col >> 1) ? 130 : 0);
      int cin = (row >= ROWS) + (row >= 2 * ROWS);
      int rr  = row - cin * ROWS;
      xs[cin][rr][wp] = 0.f;
    }
  }
  __syncthreads();

  const int w  = t & 127;
  const int cg = t >> 7;                              // wave-uniform
  const int c  = __builtin_amdgcn_readfirstlane(cp * 2 + cg);

  // wave-uniform weights -> scalar loads
  const float kwa = kwp[c * 3], kwb = kwp[c * 3 + 1], kwc = kwp[c * 3 + 2];
  const float vwa = vwp[c * 3], vwb = vwp[c * 3 + 1], vwc = vwp[c * 3 + 2];
  const float qwa = qwp[c * 3], qwb = qwp[c * 3 + 1], qwc = qwp[c * 3 + 2];

  const float ea_c = ea[c * 128 + w];                 // h-invariant, hoisted
  const float* ebp = eb + c * 128 + h0;               // uniform per step
  const float* emp = em + (c * 128 + h0) * 128 + w;
  float* outp = out + ((b * 64 + c) * 128 + h0) * 128 + w;

  // sliding tap window: kk[j]/vv[j] = f4 over row-slots for window col j
  f4 kk[4], vv[4];

#define SLIDE(RR, COMP)                                        \
  do {                                                         \
    _Pragma("unroll")                                          \
    for (int j = 0; j < 4; ++j) {                              \
      float x0 = xs[0][RR][w + j];                             \
      float x1 = xs[1][RR][w + j];                             \
      float x2 = xs[2][RR][w + j];                             \
      kk[j][COMP] = kwc * x2 + (kwa * x0 + kwb * x1);          \
      vv[j][COMP] = vwc * x2 + (vwa * x0 + vwb * x1);          \
    }                                                          \
  } while (0)

  // prologue: window rows rr=0,1,2 into slots 0,1,2
  SLIDE(0, 0);
  SLIDE(1, 1);
  SLIDE(2, 2);

  float em_cur = emp[0];

#pragma unroll 1
  for (int s4 = 0; s4 < TILE / 4; ++s4) {
#pragma unroll
    for (int phi = 0; phi < 4; ++phi) {
      const int s = s4 * 4 + phi;          // output row h0+s
      SLIDE(s + 3, ((phi + 3) & 3));       // entering row -> retiring slot

      // prefetch next-step em (clamped dummy on last step)
      const float em_nxt = emp[(s + 1 < TILE ? s + 1 : s) * 128];
      const float eb_s = ebp[s];           // uniform -> s_load (K$-hot)

      // q conv at (h, w): staged row s+2, col w+2
      const float q = qwa * xs[0][s + 2][w + 2] + qwb * xs[1][s + 2][w + 2] +
                      qwc * xs[2][s + 2][w + 2];

      // scalar embedding factor shared by all 16 taps (log2 domain)
      const float sp = (ea_c + eb_s) * em_cur * LOG2E;

      // embedding logits tl = sp * v^2, per window column
      f4 e0 = (sp * vv[0]) * vv[0];
      f4 e1 = (sp * vv[1]) * vv[1];
      f4 e2 = (sp * vv[2]) * vv[2];
      f4 e3 = (sp * vv[3]) * vv[3];

      f4 mm = fmax4(fmax4(e0, e1), fmax4(e2, e3));
      const float tmax = fmaxf(fmaxf(mm.x, mm.y), fmaxf(mm.z, mm.w));

      // e = 2^(tl - tmax); embedding-softmax normalization folded into qs
      e0 = vexp2(e0 - tmax);
      e1 = vexp2(e1 - tmax);
      e2 = vexp2(e2 - tmax);
      e3 = vexp2(e3 - tmax);

      f4 se = (e0 + e1) + (e2 + e3);
      const float sum_e = (se.x + se.y) + (se.z + se.w);
      const float qs = q * LOG2E * __builtin_amdgcn_rcpf(sum_e);

      // att: p = 2^(qs * k * e); |arg| <~ 4 -> no max-subtraction needed
      f4 p0 = vexp2((qs * kk[0]) * e0);
      f4 p1 = vexp2((qs * kk[1]) * e1);
      f4 p2 = vexp2((qs * kk[2]) * e2);
      f4 p3 = vexp2((qs * kk[3]) * e3);

      f4 ps = (p0 + p1) + (p2 + p3);
      f4 pv = (p0 * vv[0] + p1 * vv[1]) + (p2 * vv[2] + p3 * vv[3]);

      const float denom = (ps.x + ps.y) + (ps.z + ps.w);
      const float numer = (pv.x + pv.y) + (pv.z + pv.w);

      outp[s * 128] = numer * __builtin_amdgcn_rcpf(denom);
      em_cur = em_nxt;
    }
  }
#undef SLIDE
}

extern "C" void kernel_launch(void* const* d_in, const int* in_sizes, int n_in,
                              void* d_out, int out_size, void* d_ws, size_t ws_size,
                              hipStream_t stream) {
  const float* x  = (const float*)d_in[0];
  const float* qw = (const float*)d_in[1];
  const float* kw = (const float*)d_in[2];
  const float* vw = (const float*)d_in[3];
  const float* ea = (const float*)d_in[4];
  const float* eb = (const float*)d_in[5];
  const float* em = (const float*)d_in[6];
  float* out = (float*)d_out;

  stem_kernel<<<dim3(8 * 8 * 32), dim3(256), 0, stream>>>(x, qw, kw, vw, ea, eb, em, out);
}

// Round 8
// 86.521 us; speedup vs baseline: 2.6313x; 2.6313x over previous
//
#include <hip/hip_runtime.h>

typedef float f4 __attribute__((ext_vector_type(4)));

static __device__ __forceinline__ f4 vexp2(f4 a) {
  f4 r;
  r.x = __builtin_amdgcn_exp2f(a.x);
  r.y = __builtin_amdgcn_exp2f(a.y);
  r.z = __builtin_amdgcn_exp2f(a.z);
  r.w = __builtin_amdgcn_exp2f(a.w);
  return r;
}

#define LOG2E 1.4426950408889634f
#define TILE 16
#define ROWS (TILE + 3)   // 19 staged padded rows per tile

// Grid: 8(b) x 8(h-tile) x 32(channel pair) = 2048 blocks, 256 threads.
// Thread = (w = t&127, cg = t>>7) owns ONE channel c = cp*2+cg and marches
// down TILE output rows. The 4x4 conv-tap window (kk/vv, f4 over row-slots
// per window column) slides in registers: each step computes only the
// entering row (24 FMA + 12 conflict-free ds_read_b32) instead of all 16.
// Slot index (phi+3)&3 is compile-time via the unrolled phi loop.
//
// VGPR cap is 256/N for __launch_bounds__(256,N) on this toolchain
// (R3: N=8 -> 32 cap, disaster; R2/R4: N=4 -> 64; R7: N=4 spilled at 64
// with this structure's ~90 live regs -> 700 MB scratch traffic).
// N=2 -> 128 cap: fits with headroom, still 16 waves/CU.
//
// Embedding softmax needs NO max-subtraction: |sp| <~ 30, v^2 <~ 4 so
// |tl| <~ 110 < 126 (no 2^tl overflow), and sum_e >= 2^-5 in practice
// (a window almost surely has a tap with v^2 ~ 0), so qs = q/sum_e is
// bounded. Saves the 16-wide max tree + 16 subtracts per output.
__global__ __launch_bounds__(256, 2) void stem_kernel(
    const float* __restrict__ x,    // [8,3,128,128]
    const float* __restrict__ qwp,  // [64,3]
    const float* __restrict__ kwp,  // [64,3]
    const float* __restrict__ vwp,  // [64,3]
    const float* __restrict__ ea,   // [64,128]  (c, w)
    const float* __restrict__ eb,   // [64,128]  (c, h)
    const float* __restrict__ em,   // [64,128,128] (c, h, w)
    float* __restrict__ out)        // [8,64,128,128]
{
  __shared__ float xs[3][ROWS][132];   // 30.1 KB

  const int blk = blockIdx.x;
  const int cp = blk & 31;           // channel pair index
  const int ht = (blk >> 5) & 7;     // h tile
  const int b  = blk >> 8;
  const int h0 = ht * TILE;
  const int t  = threadIdx.x;

  // ---- stage: interior cols via shift-only addressing, pads separately.
  {
    const float* xb = x + b * (3 * 128 * 128);
    for (int idx = t; idx < 3 * ROWS * 128; idx += 256) {
      int row = idx >> 7;                 // 0..56 = cin*ROWS + rr
      int wp2 = idx & 127;                // dest col wp2+2, source col wp2
      int cin = (row >= ROWS) + (row >= 2 * ROWS);
      int rr  = row - cin * ROWS;
      int g   = h0 - 2 + rr;              // source row (may be OOB -> 0)
      float v = 0.f;
      if ((unsigned)g < 128u) v = xb[(cin * 128 + g) * 128 + wp2];
      xs[cin][rr][wp2 + 2] = v;
    }
    if (t < 3 * ROWS * 4) {               // pad cols {0,1,130,131} = 0
      int row = t >> 2;
      int col = t & 3;
      int wp  = (col & 1) + ((col >> 1) ? 130 : 0);
      int cin = (row >= ROWS) + (row >= 2 * ROWS);
      int rr  = row - cin * ROWS;
      xs[cin][rr][wp] = 0.f;
    }
  }
  __syncthreads();

  const int w  = t & 127;
  const int cg = t >> 7;                              // wave-uniform
  const int c  = __builtin_amdgcn_readfirstlane(cp * 2 + cg);

  // wave-uniform weights -> scalar loads (SGPRs)
  const float kwa = kwp[c * 3], kwb = kwp[c * 3 + 1], kwc = kwp[c * 3 + 2];
  const float vwa = vwp[c * 3], vwb = vwp[c * 3 + 1], vwc = vwp[c * 3 + 2];
  const float qwa = qwp[c * 3], qwb = qwp[c * 3 + 1], qwc = qwp[c * 3 + 2];

  const float ea_c = ea[c * 128 + w];                 // h-invariant, hoisted
  const float* ebp = eb + c * 128 + h0;               // uniform per step
  const float* emp = em + (c * 128 + h0) * 128 + w;
  float* outp = out + ((b * 64 + c) * 128 + h0) * 128 + w;

  // sliding tap window + stash of x at col w+2 of the last-slid row
  // (the q-conv inputs for the NEXT step, saving 3 LDS reads/step)
  f4 kk[4], vv[4];
  float qx0, qx1, qx2;

#define SLIDE(RR, COMP)                                        \
  do {                                                         \
    _Pragma("unroll")                                          \
    for (int j = 0; j < 4; ++j) {                              \
      float x0 = xs[0][RR][w + j];                             \
      float x1 = xs[1][RR][w + j];                             \
      float x2 = xs[2][RR][w + j];                             \
      kk[j][COMP] = kwc * x2 + (kwa * x0 + kwb * x1);          \
      vv[j][COMP] = vwc * x2 + (vwa * x0 + vwb * x1);          \
      if (j == 2) { qx0 = x0; qx1 = x1; qx2 = x2; }            \
    }                                                          \
  } while (0)

  // prologue: window rows rr=0,1,2 into slots 0,1,2; stash = row 2 (q row s=0)
  SLIDE(0, 0);
  SLIDE(1, 1);
  SLIDE(2, 2);

  float em_cur = emp[0];

#pragma unroll 1
  for (int s4 = 0; s4 < TILE / 4; ++s4) {
#pragma unroll
    for (int phi = 0; phi < 4; ++phi) {
      const int s = s4 * 4 + phi;          // output row h0+s

      // q conv at (h0+s, w) from the stash (row s+2), BEFORE SLIDE clobbers it
      const float q = qwa * qx0 + qwb * qx1 + qwc * qx2;

      SLIDE(s + 3, ((phi + 3) & 3));       // entering row -> retiring slot

      // prefetch next-step em (clamped dummy on last step)
      const float em_nxt = emp[(s + 1 < TILE ? s + 1 : s) * 128];
      const float eb_s = ebp[s];           // uniform -> s_load (K$-hot)

      // scalar embedding factor shared by all 16 taps (log2 domain)
      const float sp = (ea_c + eb_s) * em_cur * LOG2E;

      // embedding weights e = 2^(sp * v^2), NO max-subtraction (see header);
      // normalization 1/sum_e folded into qs.
      f4 e0 = vexp2((sp * vv[0]) * vv[0]);
      f4 e1 = vexp2((sp * vv[1]) * vv[1]);
      f4 e2 = vexp2((sp * vv[2]) * vv[2]);
      f4 e3 = vexp2((sp * vv[3]) * vv[3]);

      f4 se = (e0 + e1) + (e2 + e3);
      const float sum_e = (se.x + se.y) + (se.z + se.w);
      const float qs = q * LOG2E * __builtin_amdgcn_rcpf(sum_e);

      // att: p = 2^(qs * k * e); |arg| <~ 4 -> no max-subtraction needed
      f4 p0 = vexp2((qs * kk[0]) * e0);
      f4 p1 = vexp2((qs * kk[1]) * e1);
      f4 p2 = vexp2((qs * kk[2]) * e2);
      f4 p3 = vexp2((qs * kk[3]) * e3);

      f4 ps = (p0 + p1) + (p2 + p3);
      f4 pv = (p0 * vv[0] + p1 * vv[1]) + (p2 * vv[2] + p3 * vv[3]);

      const float denom = (ps.x + ps.y) + (ps.z + ps.w);
      const float numer = (pv.x + pv.y) + (pv.z + pv.w);

      outp[s * 128] = numer * __builtin_amdgcn_rcpf(denom);
      em_cur = em_nxt;
    }
  }
#undef SLIDE
}

extern "C" void kernel_launch(void* const* d_in, const int* in_sizes, int n_in,
                              void* d_out, int out_size, void* d_ws, size_t ws_size,
                              hipStream_t stream) {
  const float* x  = (const float*)d_in[0];
  const float* qw = (const float*)d_in[1];
  const float* kw = (const float*)d_in[2];
  const float* vw = (const float*)d_in[3];
  const float* ea = (const float*)d_in[4];
  const float* eb = (const float*)d_in[5];
  const float* em = (const float*)d_in[6];
  float* out = (float*)d_out;

  stem_kernel<<<dim3(8 * 8 * 32), dim3(256), 0, stream>>>(x, qw, kw, vw, ea, eb, em, out);
}

// Round 9
// 63.532 us; speedup vs baseline: 3.5835x; 1.3618x over previous
//
#include <hip/hip_runtime.h>

typedef float f4 __attribute__((ext_vector_type(4)));

static __device__ __forceinline__ f4 vexp2(f4 a) {
  f4 r;
  r.x = __builtin_amdgcn_exp2f(a.x);
  r.y = __builtin_amdgcn_exp2f(a.y);
  r.z = __builtin_amdgcn_exp2f(a.z);
  r.w = __builtin_amdgcn_exp2f(a.w);
  return r;
}

#define LOG2E 1.4426950408889634f
#define TILE 8
#define ROWS (TILE + 3)   // 11 staged padded rows per tile

// Grid: 8(b) x 16(h-tile) x 32(channel pair) = 4096 blocks, 256 threads.
// Thread = (w = t&127, cg = t>>7) owns ONE channel c = cp*2+cg and marches
// down TILE=8 output rows. The 4x4 conv-tap window (kk/vv, f4 over row-slots
// per window column) slides in registers; the row loop is FULLY UNROLLED so
// (a) every xs[][][] read is one ds_read_b32 with a compile-time immediate
//     offset off a single w*4 vaddr (no per-step address VALU — R8's hidden
//     cost), and
// (b) the compiler can software-pipeline the two dependent exp stages of
//     step s with the SLIDE/e-stage of step s+1 (kk/vv of s+1 don't depend
//     on outputs of s), hiding trans latency without extra occupancy.
//
// VGPR cap is 256/N for __launch_bounds__(256,N) (R3: N=8 -> 32, disaster;
// R7: N=4 -> 64, spilled; R8: N=2 -> 104 used, no spill). Keep N=2.
// No-max softmax for BOTH exp stages: R8 validated absmax unchanged
// (embedding logits |tl|<~110 < 126, att logits |z|<~4).
// Plain C++ vector math only (R5: inline-asm v_pk_* broke correctness).
__global__ __launch_bounds__(256, 2) void stem_kernel(
    const float* __restrict__ x,    // [8,3,128,128]
    const float* __restrict__ qwp,  // [64,3]
    const float* __restrict__ kwp,  // [64,3]
    const float* __restrict__ vwp,  // [64,3]
    const float* __restrict__ ea,   // [64,128]  (c, w)
    const float* __restrict__ eb,   // [64,128]  (c, h)
    const float* __restrict__ em,   // [64,128,128] (c, h, w)
    float* __restrict__ out)        // [8,64,128,128]
{
  __shared__ float xs[3][ROWS][132];   // 17.4 KB

  const int blk = blockIdx.x;
  const int cp = blk & 31;            // channel pair index
  const int ht = (blk >> 5) & 15;     // h tile
  const int b  = blk >> 9;
  const int h0 = ht * TILE;
  const int t  = threadIdx.x;

  // ---- stage: interior cols via shift-only addressing, pads separately.
  {
    const float* xb = x + b * (3 * 128 * 128);
    for (int idx = t; idx < 3 * ROWS * 128; idx += 256) {
      int row = idx >> 7;                 // cin*ROWS + rr
      int wp2 = idx & 127;                // dest col wp2+2, source col wp2
      int cin = (row >= ROWS) + (row >= 2 * ROWS);
      int rr  = row - cin * ROWS;
      int g   = h0 - 2 + rr;              // source row (may be OOB -> 0)
      float v = 0.f;
      if ((unsigned)g < 128u) v = xb[(cin * 128 + g) * 128 + wp2];
      xs[cin][rr][wp2 + 2] = v;
    }
    if (t < 3 * ROWS * 4) {               // pad cols {0,1,130,131} = 0
      int row = t >> 2;
      int col = t & 3;
      int wp  = (col & 1) + ((col >> 1) ? 130 : 0);
      int cin = (row >= ROWS) + (row >= 2 * ROWS);
      int rr  = row - cin * ROWS;
      xs[cin][rr][wp] = 0.f;
    }
  }
  __syncthreads();

  const int w  = t & 127;
  const int cg = t >> 7;                              // wave-uniform
  const int c  = __builtin_amdgcn_readfirstlane(cp * 2 + cg);

  // wave-uniform weights -> scalar loads (SGPRs); LOG2E folded into qw
  const float kwa = kwp[c * 3], kwb = kwp[c * 3 + 1], kwc = kwp[c * 3 + 2];
  const float vwa = vwp[c * 3], vwb = vwp[c * 3 + 1], vwc = vwp[c * 3 + 2];
  const float qwa = qwp[c * 3] * LOG2E, qwb = qwp[c * 3 + 1] * LOG2E,
              qwc = qwp[c * 3 + 2] * LOG2E;

  const float ea_c = ea[c * 128 + w];                 // h-invariant, hoisted
  const float* ebp = eb + c * 128 + h0;               // uniform -> s_loads
  const float* emp = em + (c * 128 + h0) * 128 + w;
  float* outp = out + ((b * 64 + c) * 128 + h0) * 128 + w;

  // sliding tap window + stash of x at col w+2 of the last-slid row
  // (q-conv inputs for the NEXT step; j==2 values are already loaded)
  f4 kk[4], vv[4];
  float qx0, qx1, qx2;

#define SLIDE(RR, COMP)                                        \
  do {                                                         \
    _Pragma("unroll")                                          \
    for (int j = 0; j < 4; ++j) {                              \
      float x0 = xs[0][RR][w + j];                             \
      float x1 = xs[1][RR][w + j];                             \
      float x2 = xs[2][RR][w + j];                             \
      kk[j][COMP] = kwc * x2 + (kwa * x0 + kwb * x1);          \
      vv[j][COMP] = vwc * x2 + (vwa * x0 + vwb * x1);          \
      if (j == 2) { qx0 = x0; qx1 = x1; qx2 = x2; }            \
    }                                                          \
  } while (0)

  // prologue: window rows rr=0,1,2 into slots 0,1,2; stash = row 2 (s=0 q row)
  SLIDE(0, 0);
  SLIDE(1, 1);
  SLIDE(2, 2);

#pragma unroll
  for (int s = 0; s < TILE; ++s) {
    // q conv (pre-scaled by LOG2E) from the stash, BEFORE SLIDE clobbers it
    const float q = qwa * qx0 + qwb * qx1 + qwc * qx2;

    SLIDE(s + 3, ((s + 3) & 3));         // entering row -> retiring slot

    const float eb_s = ebp[s];           // uniform -> s_load
    const float sp = (ea_c + eb_s) * emp[s * 128] * LOG2E;

    // embedding weights e = 2^(sp * v^2), no max-subtraction (R8-validated);
    // normalization 1/sum_e folded into qs.
    f4 e0 = vexp2((sp * vv[0]) * vv[0]);
    f4 e1 = vexp2((sp * vv[1]) * vv[1]);
    f4 e2 = vexp2((sp * vv[2]) * vv[2]);
    f4 e3 = vexp2((sp * vv[3]) * vv[3]);

    f4 se = (e0 + e1) + (e2 + e3);
    const float sum_e = (se.x + se.y) + (se.z + se.w);
    const float qs = q * __builtin_amdgcn_rcpf(sum_e);  // LOG2E already in q

    // att: p = 2^(qs * k * e); |arg| <~ 4 -> no max-subtraction needed
    f4 p0 = vexp2((qs * kk[0]) * e0);
    f4 p1 = vexp2((qs * kk[1]) * e1);
    f4 p2 = vexp2((qs * kk[2]) * e2);
    f4 p3 = vexp2((qs * kk[3]) * e3);

    f4 ps = (p0 + p1) + (p2 + p3);
    f4 pv = (p0 * vv[0] + p1 * vv[1]) + (p2 * vv[2] + p3 * vv[3]);

    const float denom = (ps.x + ps.y) + (ps.z + ps.w);
    const float numer = (pv.x + pv.y) + (pv.z + pv.w);

    outp[s * 128] = numer * __builtin_amdgcn_rcpf(denom);
  }
#undef SLIDE
}

extern "C" void kernel_launch(void* const* d_in, const int* in_sizes, int n_in,
                              void* d_out, int out_size, void* d_ws, size_t ws_size,
                              hipStream_t stream) {
  const float* x  = (const float*)d_in[0];
  const float* qw = (const float*)d_in[1];
  const float* kw = (const float*)d_in[2];
  const float* vw = (const float*)d_in[3];
  const float* ea = (const float*)d_in[4];
  const float* eb = (const float*)d_in[5];
  const float* em = (const float*)d_in[6];
  float* out = (float*)d_out;

  stem_kernel<<<dim3(8 * 16 * 32), dim3(256), 0, stream>>>(x, qw, kw, vw, ea, eb, em, out);
}

// Round 10
// 58.094 us; speedup vs baseline: 3.9189x; 1.0936x over previous
//
#include <hip/hip_runtime.h>

typedef float f4 __attribute__((ext_vector_type(4)));

static __device__ __forceinline__ f4 vexp2(f4 a) {
  f4 r;
  r.x = __builtin_amdgcn_exp2f(a.x);
  r.y = __builtin_amdgcn_exp2f(a.y);
  r.z = __builtin_amdgcn_exp2f(a.z);
  r.w = __builtin_amdgcn_exp2f(a.w);
  return r;
}

#define LOG2E 1.4426950408889634f
#define TILE 8
#define ROWS (TILE + 3)   // 11 staged padded rows per tile

// Grid: 8(b) x 16(h-tile) x 16(channel quad) = 2048 blocks, 512 threads.
// Thread = (w = t&127, cg = t>>7 in 0..3) owns ONE channel c = cq*4+cg and
// marches down TILE=8 output rows. One 17.4 KB x-stage serves 4 channels
// (vs 2 in R9): staging VALU per output halves, and 8 waves/block fill the
// CU better (4 blocks x 8 waves = 32 waves/CU possible).
// Sliding register window: kk/vv/vsq (f4 over row-slots per window column);
// row loop FULLY UNROLLED so all LDS reads are imm-offset ds_read_b32 off
// one w*4 vaddr and cross-step ILP hides the exp chains (R9-proven).
// vsq = v^2 cached in the slide (+4 muls) so the e-stage is 16 muls, not 32.
//
// VGPR cap is 256/N for __launch_bounds__(.,N) (R3: N=8 -> 32, disaster;
// R7: N=4 -> 64, spilled; R8/R9: N=2 -> 104/52 used, no spill). Keep N=2.
// No-max softmax both stages (R8/R9-validated: |tl|<~110 < 126, |z|<~4).
// Plain C++ vector math only (R5: inline-asm v_pk_* broke correctness).
__global__ __launch_bounds__(512, 2) void stem_kernel(
    const float* __restrict__ x,    // [8,3,128,128]
    const float* __restrict__ qwp,  // [64,3]
    const float* __restrict__ kwp,  // [64,3]
    const float* __restrict__ vwp,  // [64,3]
    const float* __restrict__ ea,   // [64,128]  (c, w)
    const float* __restrict__ eb,   // [64,128]  (c, h)
    const float* __restrict__ em,   // [64,128,128] (c, h, w)
    float* __restrict__ out)        // [8,64,128,128]
{
  __shared__ float xs[3][ROWS][132];   // 17.4 KB

  const int blk = blockIdx.x;
  const int cq = blk & 15;            // channel quad index
  const int ht = (blk >> 4) & 15;     // h tile
  const int b  = blk >> 8;
  const int h0 = ht * TILE;
  const int t  = threadIdx.x;

  // ---- stage: interior cols via shift-only addressing, pads separately.
  {
    const float* xb = x + b * (3 * 128 * 128);
    for (int idx = t; idx < 3 * ROWS * 128; idx += 512) {
      int row = idx >> 7;                 // cin*ROWS + rr
      int wp2 = idx & 127;                // dest col wp2+2, source col wp2
      int cin = (row >= ROWS) + (row >= 2 * ROWS);
      int rr  = row - cin * ROWS;
      int g   = h0 - 2 + rr;              // source row (may be OOB -> 0)
      float v = 0.f;
      if ((unsigned)g < 128u) v = xb[(cin * 128 + g) * 128 + wp2];
      xs[cin][rr][wp2 + 2] = v;
    }
    if (t < 3 * ROWS * 4) {               // pad cols {0,1,130,131} = 0
      int row = t >> 2;
      int col = t & 3;
      int wp  = (col & 1) + ((col >> 1) ? 130 : 0);
      int cin = (row >= ROWS) + (row >= 2 * ROWS);
      int rr  = row - cin * ROWS;
      xs[cin][rr][wp] = 0.f;
    }
  }
  __syncthreads();

  const int w  = t & 127;
  const int cg = t >> 7;                              // wave-uniform (t/128)
  const int c  = __builtin_amdgcn_readfirstlane(cq * 4 + cg);

  // wave-uniform weights -> scalar loads (SGPRs); LOG2E folded into qw
  const float kwa = kwp[c * 3], kwb = kwp[c * 3 + 1], kwc = kwp[c * 3 + 2];
  const float vwa = vwp[c * 3], vwb = vwp[c * 3 + 1], vwc = vwp[c * 3 + 2];
  const float qwa = qwp[c * 3] * LOG2E, qwb = qwp[c * 3 + 1] * LOG2E,
              qwc = qwp[c * 3 + 2] * LOG2E;

  const float ea_c = ea[c * 128 + w];                 // h-invariant, hoisted
  const float* ebp = eb + c * 128 + h0;               // uniform -> s_loads
  const float* emp = em + (c * 128 + h0) * 128 + w;
  float* outp = out + ((b * 64 + c) * 128 + h0) * 128 + w;

  // sliding tap window (+ v^2 cache) + stash of x at col w+2 of the
  // last-slid row (q-conv inputs for the NEXT step)
  f4 kk[4], vv[4], vsq[4];
  float qx0, qx1, qx2;

#define SLIDE(RR, COMP)                                        \
  do {                                                         \
    _Pragma("unroll")                                          \
    for (int j = 0; j < 4; ++j) {                              \
      float x0 = xs[0][RR][w + j];                             \
      float x1 = xs[1][RR][w + j];                             \
      float x2 = xs[2][RR][w + j];                             \
      float kn = kwc * x2 + (kwa * x0 + kwb * x1);             \
      float vn = vwc * x2 + (vwa * x0 + vwb * x1);             \
      kk[j][COMP] = kn;                                        \
      vv[j][COMP] = vn;                                        \
      vsq[j][COMP] = vn * vn;                                  \
      if (j == 2) { qx0 = x0; qx1 = x1; qx2 = x2; }            \
    }                                                          \
  } while (0)

  // prologue: window rows rr=0,1,2 into slots 0,1,2; stash = row 2 (s=0 q row)
  SLIDE(0, 0);
  SLIDE(1, 1);
  SLIDE(2, 2);

#pragma unroll
  for (int s = 0; s < TILE; ++s) {
    // q conv (pre-scaled by LOG2E) from the stash, BEFORE SLIDE clobbers it
    const float q = qwa * qx0 + qwb * qx1 + qwc * qx2;

    SLIDE(s + 3, ((s + 3) & 3));         // entering row -> retiring slot

    const float eb_s = ebp[s];           // uniform -> s_load
    const float sp = (ea_c + eb_s) * emp[s * 128] * LOG2E;

    // embedding weights e = 2^(sp * v^2) via cached vsq (16 muls);
    // no max-subtraction (R8/R9-validated); 1/sum_e folded into qs.
    f4 e0 = vexp2(sp * vsq[0]);
    f4 e1 = vexp2(sp * vsq[1]);
    f4 e2 = vexp2(sp * vsq[2]);
    f4 e3 = vexp2(sp * vsq[3]);

    f4 se = (e0 + e1) + (e2 + e3);
    const float sum_e = (se.x + se.y) + (se.z + se.w);
    const float qs = q * __builtin_amdgcn_rcpf(sum_e);  // LOG2E already in q

    // att: p = 2^(qs * k * e); |arg| <~ 4 -> no max-subtraction needed
    f4 p0 = vexp2((qs * kk[0]) * e0);
    f4 p1 = vexp2((qs * kk[1]) * e1);
    f4 p2 = vexp2((qs * kk[2]) * e2);
    f4 p3 = vexp2((qs * kk[3]) * e3);

    f4 ps = (p0 + p1) + (p2 + p3);
    f4 pv = (p0 * vv[0] + p1 * vv[1]) + (p2 * vv[2] + p3 * vv[3]);

    const float denom = (ps.x + ps.y) + (ps.z + ps.w);
    const float numer = (pv.x + pv.y) + (pv.z + pv.w);

    outp[s * 128] = numer * __builtin_amdgcn_rcpf(denom);
  }
#undef SLIDE
}

extern "C" void kernel_launch(void* const* d_in, const int* in_sizes, int n_in,
                              void* d_out, int out_size, void* d_ws, size_t ws_size,
                              hipStream_t stream) {
  const float* x  = (const float*)d_in[0];
  const float* qw = (const float*)d_in[1];
  const float* kw = (const float*)d_in[2];
  const float* vw = (const float*)d_in[3];
  const float* ea = (const float*)d_in[4];
  const float* eb = (const float*)d_in[5];
  const float* em = (const float*)d_in[6];
  float* out = (float*)d_out;

  stem_kernel<<<dim3(8 * 16 * 16), dim3(512), 0, stream>>>(x, qw, kw, vw, ea, eb, em, out);
}

// Round 11
// 55.531 us; speedup vs baseline: 4.0998x; 1.0461x over previous
//
#include <hip/hip_runtime.h>

typedef float f4 __attribute__((ext_vector_type(4)));

static __device__ __forceinline__ f4 vexp2(f4 a) {
  f4 r;
  r.x = __builtin_amdgcn_exp2f(a.x);
  r.y = __builtin_amdgcn_exp2f(a.y);
  r.z = __builtin_amdgcn_exp2f(a.z);
  r.w = __builtin_amdgcn_exp2f(a.w);
  return r;
}

#define LOG2E 1.4426950408889634f
#define TILE 8
#define ROWS (TILE + 3)   // 11 staged padded rows per tile

// Grid: 8(b) x 16(h-tile) x 8(channel quad) = 1024 blocks, 512 threads.
// Thread = (w = t&127, cg = t>>7 in 0..3) owns TWO channels c0 = cq*4+cg
// and c1 = c0+32, marching down TILE=8 output rows. Rationale (R10 post-
// mortem): VALU-busy-time was insensitive to instruction count across
// rounds and VALUBusy pinned ~72% at ~2.6 effective waves/SIMD -> each
// step's serial chain (LDS->conv->exp->sum->rcp->exp->sum->rcp) is
// latency-bound. Two independent softmax chains per thread double ILP at
// every latency point, and the shared x-window halves LDS reads/output.
// vsq cache dropped (+16 muls/output) to fit the 128-VGPR cap.
//
// VGPR cap is 256/N for __launch_bounds__(.,N) (R3: N=8 -> 32, disaster;
// R7: N=4 -> 64, spilled; R8/R9/R10: N=2 -> 104/52/60 used, no spill).
// No-max softmax both stages (R8-R10-validated: |tl|<~110 < 126, |z|<~4).
// Plain C++ vector math only (R5: inline-asm v_pk_* broke correctness).
__global__ __launch_bounds__(512, 2) void stem_kernel(
    const float* __restrict__ x,    // [8,3,128,128]
    const float* __restrict__ qwp,  // [64,3]
    const float* __restrict__ kwp,  // [64,3]
    const float* __restrict__ vwp,  // [64,3]
    const float* __restrict__ ea,   // [64,128]  (c, w)
    const float* __restrict__ eb,   // [64,128]  (c, h)
    const float* __restrict__ em,   // [64,128,128] (c, h, w)
    float* __restrict__ out)        // [8,64,128,128]
{
  __shared__ float xs[3][ROWS][132];   // 17.4 KB

  const int blk = blockIdx.x;
  const int cq = blk & 7;             // channel quad (low half)
  const int ht = (blk >> 3) & 15;     // h tile
  const int b  = blk >> 7;
  const int h0 = ht * TILE;
  const int t  = threadIdx.x;

  // ---- stage: interior cols via shift-only addressing, pads separately.
  {
    const float* xb = x + b * (3 * 128 * 128);
    for (int idx = t; idx < 3 * ROWS * 128; idx += 512) {
      int row = idx >> 7;                 // cin*ROWS + rr
      int wp2 = idx & 127;                // dest col wp2+2, source col wp2
      int cin = (row >= ROWS) + (row >= 2 * ROWS);
      int rr  = row - cin * ROWS;
      int g   = h0 - 2 + rr;              // source row (may be OOB -> 0)
      float v = 0.f;
      if ((unsigned)g < 128u) v = xb[(cin * 128 + g) * 128 + wp2];
      xs[cin][rr][wp2 + 2] = v;
    }
    if (t < 3 * ROWS * 4) {               // pad cols {0,1,130,131} = 0
      int row = t >> 2;
      int col = t & 3;
      int wp  = (col & 1) + ((col >> 1) ? 130 : 0);
      int cin = (row >= ROWS) + (row >= 2 * ROWS);
      int rr  = row - cin * ROWS;
      xs[cin][rr][wp] = 0.f;
    }
  }
  __syncthreads();

  const int w  = t & 127;
  const int cg = t >> 7;                              // wave-uniform
  const int c0 = __builtin_amdgcn_readfirstlane(cq * 4 + cg);
  const int c1 = c0 + 32;

  // wave-uniform weights -> scalar loads (SGPRs); LOG2E folded into qw
  const float kwa0 = kwp[c0 * 3], kwb0 = kwp[c0 * 3 + 1], kwc0 = kwp[c0 * 3 + 2];
  const float kwa1 = kwp[c1 * 3], kwb1 = kwp[c1 * 3 + 1], kwc1 = kwp[c1 * 3 + 2];
  const float vwa0 = vwp[c0 * 3], vwb0 = vwp[c0 * 3 + 1], vwc0 = vwp[c0 * 3 + 2];
  const float vwa1 = vwp[c1 * 3], vwb1 = vwp[c1 * 3 + 1], vwc1 = vwp[c1 * 3 + 2];
  const float qwa0 = qwp[c0 * 3] * LOG2E, qwb0 = qwp[c0 * 3 + 1] * LOG2E,
              qwc0 = qwp[c0 * 3 + 2] * LOG2E;
  const float qwa1 = qwp[c1 * 3] * LOG2E, qwb1 = qwp[c1 * 3 + 1] * LOG2E,
              qwc1 = qwp[c1 * 3 + 2] * LOG2E;

  const float ea0 = ea[c0 * 128 + w];                 // h-invariant, hoisted
  const float ea1 = ea[c1 * 128 + w];
  const float* ebp0 = eb + c0 * 128 + h0;             // uniform -> s_loads
  const float* ebp1 = eb + c1 * 128 + h0;
  const float* emp0 = em + (c0 * 128 + h0) * 128 + w;
  const float* emp1 = em + (c1 * 128 + h0) * 128 + w;
  float* outp0 = out + ((b * 64 + c0) * 128 + h0) * 128 + w;
  float* outp1 = out + ((b * 64 + c1) * 128 + h0) * 128 + w;

  // sliding tap windows for BOTH channels + shared q-conv stash (col w+2
  // of the last-slid row = the q inputs for the NEXT step)
  f4 kk0[4], vv0[4], kk1[4], vv1[4];
  float qx0, qx1, qx2;

#define SLIDE(RR, COMP)                                        \
  do {                                                         \
    _Pragma("unroll")                                          \
    for (int j = 0; j < 4; ++j) {                              \
      float x0 = xs[0][RR][w + j];                             \
      float x1 = xs[1][RR][w + j];                             \
      float x2 = xs[2][RR][w + j];                             \
      kk0[j][COMP] = kwc0 * x2 + (kwa0 * x0 + kwb0 * x1);      \
      vv0[j][COMP] = vwc0 * x2 + (vwa0 * x0 + vwb0 * x1);      \
      kk1[j][COMP] = kwc1 * x2 + (kwa1 * x0 + kwb1 * x1);      \
      vv1[j][COMP] = vwc1 * x2 + (vwa1 * x0 + vwb1 * x1);      \
      if (j == 2) { qx0 = x0; qx1 = x1; qx2 = x2; }            \
    }                                                          \
  } while (0)

  // prologue: window rows rr=0,1,2 into slots 0,1,2; stash = row 2 (s=0 q row)
  SLIDE(0, 0);
  SLIDE(1, 1);
  SLIDE(2, 2);

#pragma unroll
  for (int s = 0; s < TILE; ++s) {
    // q convs (pre-scaled by LOG2E) from the stash, BEFORE SLIDE clobbers it
    const float q0 = qwa0 * qx0 + qwb0 * qx1 + qwc0 * qx2;
    const float q1 = qwa1 * qx0 + qwb1 * qx1 + qwc1 * qx2;

    SLIDE(s + 3, ((s + 3) & 3));         // entering row -> retiring slot

    const float sp0 = (ea0 + ebp0[s]) * emp0[s * 128] * LOG2E;
    const float sp1 = (ea1 + ebp1[s]) * emp1[s * 128] * LOG2E;

    // embedding weights e = 2^(sp * v^2), no max-subtraction; the two
    // channels' exp chains are independent -> back-to-back issue.
    f4 e00 = vexp2((sp0 * vv0[0]) * vv0[0]);
    f4 e01 = vexp2((sp0 * vv0[1]) * vv0[1]);
    f4 e02 = vexp2((sp0 * vv0[2]) * vv0[2]);
    f4 e03 = vexp2((sp0 * vv0[3]) * vv0[3]);
    f4 e10 = vexp2((sp1 * vv1[0]) * vv1[0]);
    f4 e11 = vexp2((sp1 * vv1[1]) * vv1[1]);
    f4 e12 = vexp2((sp1 * vv1[2]) * vv1[2]);
    f4 e13 = vexp2((sp1 * vv1[3]) * vv1[3]);

    f4 se0 = (e00 + e01) + (e02 + e03);
    f4 se1 = (e10 + e11) + (e12 + e13);
    const float sum0 = (se0.x + se0.y) + (se0.z + se0.w);
    const float sum1 = (se1.x + se1.y) + (se1.z + se1.w);
    const float qs0 = q0 * __builtin_amdgcn_rcpf(sum0);  // LOG2E already in q
    const float qs1 = q1 * __builtin_amdgcn_rcpf(sum1);

    // att: p = 2^(qs * k * e); |arg| <~ 4 -> no max-subtraction needed
    f4 p00 = vexp2((qs0 * kk0[0]) * e00);
    f4 p01 = vexp2((qs0 * kk0[1]) * e01);
    f4 p02 = vexp2((qs0 * kk0[2]) * e02);
    f4 p03 = vexp2((qs0 * kk0[3]) * e03);
    f4 p10 = vexp2((qs1 * kk1[0]) * e10);
    f4 p11 = vexp2((qs1 * kk1[1]) * e11);
    f4 p12 = vexp2((qs1 * kk1[2]) * e12);
    f4 p13 = vexp2((qs1 * kk1[3]) * e13);

    f4 ps0 = (p00 + p01) + (p02 + p03);
    f4 ps1 = (p10 + p11) + (p12 + p13);
    f4 pv0 = (p00 * vv0[0] + p01 * vv0[1]) + (p02 * vv0[2] + p03 * vv0[3]);
    f4 pv1 = (p10 * vv1[0] + p11 * vv1[1]) + (p12 * vv1[2] + p13 * vv1[3]);

    const float den0 = (ps0.x + ps0.y) + (ps0.z + ps0.w);
    const float den1 = (ps1.x + ps1.y) + (ps1.z + ps1.w);
    const float num0 = (pv0.x + pv0.y) + (pv0.z + pv0.w);
    const float num1 = (pv1.x + pv1.y) + (pv1.z + pv1.w);

    outp0[s * 128] = num0 * __builtin_amdgcn_rcpf(den0);
    outp1[s * 128] = num1 * __builtin_amdgcn_rcpf(den1);
  }
#undef SLIDE
}

extern "C" void kernel_launch(void* const* d_in, const int* in_sizes, int n_in,
                              void* d_out, int out_size, void* d_ws, size_t ws_size,
                              hipStream_t stream) {
  const float* x  = (const float*)d_in[0];
  const float* qw = (const float*)d_in[1];
  const float* kw = (const float*)d_in[2];
  const float* vw = (const float*)d_in[3];
  const float* ea = (const float*)d_in[4];
  const float* eb = (const float*)d_in[5];
  const float* em = (const float*)d_in[6];
  float* out = (float*)d_out;

  stem_kernel<<<dim3(8 * 16 * 8), dim3(512), 0, stream>>>(x, qw, kw, vw, ea, eb, em, out);
}